// Round 9
// baseline (58.503 us; speedup 1.0000x reference)
//
#include <hip/hip_runtime.h>
#include <math.h>
#include <stdint.h>

#define NIMG 8
#define HH 1024
#define WW 1024
#define NPIX (HH*WW)
#define PAIRS 10000
#define STRIP 8
#define NSTRIPS 128          // strips per image (rows 1..1022, 8 rows each)
#define S1BLOCKS 40          // sample blocks per image
#define SEGCAP 30720         // max eq segments per image (>= PAIRS*3)

// ws layout (floats):
// [OFF_EDGE .. +1024)   per-strip squared-sobel max (plain stores, kernel1)
// [OFF_RES  .. +16)     per-image {loss, cnt} atomic accum        } zeroed by
// [OFF_MDI  .. +8)      per-image maxdiff (float-as-uint atomicMax)} kernel1
// [OFF_DONE .. +8)      per-image sample-done counters             } (replay-
// [OFF_IMGD]            image-finisher counter                     }  safe:
// [OFF_SEGC .. +8)      per-image eq-segment counters              }  boundary)
// byte 65536: segs float2[NIMG][SEGCAP] = {d2, ad} compacted eq segments
#define OFF_EDGE 0
#define OFF_RES  4096
#define OFF_MDI  4112
#define OFF_DONE 4120
#define OFF_IMGD 4128
#define OFF_SEGC 4136
#define ZERO_N   48          // zero ws[4096 .. 4096+48)

__device__ __forceinline__ uint64_t mix64(uint64_t x){
    x += 0x9E3779B97F4A7C15ull;
    x = (x ^ (x >> 30)) * 0xBF58476D1CE4E5B9ull;
    x = (x ^ (x >> 27)) * 0x94D049BB133111EBull;
    return x ^ (x >> 31);
}

__device__ __forceinline__ float block_reduce_max(float v, float* sm){
    for (int off = 32; off; off >>= 1)
        v = fmaxf(v, __shfl_down(v, off));
    int wv = threadIdx.x >> 6, lane = threadIdx.x & 63;
    if (lane == 0) sm[wv] = v;
    __syncthreads();
    if (threadIdx.x == 0)
        sm[0] = fmaxf(fmaxf(sm[0], sm[1]), fmaxf(sm[2], sm[3]));
    __syncthreads();
    float r = sm[0];
    __syncthreads();
    return r;
}

__device__ __forceinline__ float block_reduce_sum(float v, float* sm){
    for (int off = 32; off; off >>= 1)
        v += __shfl_down(v, off);
    int wv = threadIdx.x >> 6, lane = threadIdx.x & 63;
    if (lane == 0) sm[wv] = v;
    __syncthreads();
    if (threadIdx.x == 0)
        sm[0] = sm[0] + sm[1] + sm[2] + sm[3];
    __syncthreads();
    float r = sm[0];
    __syncthreads();
    return r;
}

__device__ __forceinline__ void sobel_at(const float* __restrict__ x, int r, int c,
                                         float& gx, float& gy){
    const float* p0 = x + (size_t)(r-1)*WW + c;
    const float* p1 = x + (size_t)r*WW + c;
    const float* p2 = x + (size_t)(r+1)*WW + c;
    float a = p0[-1], b = p0[0], cc = p0[1];
    float d = p1[-1],             e = p1[1];
    float f = p2[-1], g = p2[0], h = p2[1];
    gx = (cc - a) + 2.0f*(e - d) + (h - f);
    gy = (a + 2.0f*b + cc) - (f + 2.0f*g + h);
}

__device__ __forceinline__ void load16(const float* __restrict__ p, float* d){
    const float4* q = (const float4*)p;
    float4 v0 = q[0], v1 = q[1], v2 = q[2], v3 = q[3];
    d[0]=v0.x; d[1]=v0.y; d[2]=v0.z; d[3]=v0.w;
    d[4]=v1.x; d[5]=v1.y; d[6]=v1.z; d[7]=v1.w;
    d[8]=v2.x; d[9]=v2.y; d[10]=v2.z; d[11]=v2.w;
    d[12]=v3.x; d[13]=v3.y; d[14]=v3.z; d[15]=v3.w;
}

// One wave owns a 1024-wide row span (16 cols/lane), rolls 3 rows in registers,
// separable sobel, cross-lane neighbors via shuffles, max of SQUARED magnitude.
// Block (0,0) zeroes this launch's atomic slots (visible to kernel2 at the
// dispatch boundary — replay-safe).
__global__ __launch_bounds__(256) void edgemax_kernel(const float* __restrict__ images,
                                                      float* __restrict__ ws){
    if (blockIdx.x == 0 && blockIdx.y == 0 && threadIdx.x < ZERO_N)
        ws[OFF_RES + threadIdx.x] = 0.0f;

    int img  = blockIdx.y;
    const float* x = images + (size_t)img * 3 * NPIX;   // channel 0
    int wv   = threadIdx.x >> 6;
    int lane = threadIdx.x & 63;
    int strip = blockIdx.x * 4 + wv;                    // 0..127
    int r0 = 1 + strip * STRIP;
    int r1 = min(r0 + STRIP - 1, HH - 2);
    int c0 = lane * 16;

    float a[16], b[16], n[16];
    load16(x + (size_t)(r0-1)*WW + c0, a);
    load16(x + (size_t)r0*WW + c0, b);

    float m = 0.0f;
    for (int r = r0; r <= r1; ++r){
        load16(x + (size_t)(r+1)*WW + c0, n);
        float sx[16], dy[16];
        #pragma unroll
        for (int i = 0; i < 16; ++i){
            sx[i] = a[i] + 2.0f*b[i] + n[i];
            dy[i] = a[i] - n[i];
        }
        float sxl = __shfl_up(sx[15], 1);
        float sxr = __shfl_down(sx[0], 1);
        float dyl = __shfl_up(dy[15], 1);
        float dyr = __shfl_down(dy[0], 1);
        #pragma unroll
        for (int j = 0; j < 16; ++j){
            float sl = (j == 0)  ? sxl : sx[j-1];
            float sr = (j == 15) ? sxr : sx[j+1];
            float dl = (j == 0)  ? dyl : dy[j-1];
            float dr = (j == 15) ? dyr : dy[j+1];
            float gx = sr - sl;
            float gy = dl + 2.0f*dy[j] + dr;
            float e2 = gx*gx + gy*gy;
            int c = c0 + j;
            if (c >= 1 && c <= WW-2) m = fmaxf(m, e2);
        }
        #pragma unroll
        for (int i = 0; i < 16; ++i){ a[i] = b[i]; b[i] = n[i]; }
    }
    for (int off = 32; off; off >>= 1)
        m = fmaxf(m, __shfl_down(m, off));
    if (lane == 0)
        ws[OFF_EDGE + img * NSTRIPS + strip] = m;
}

// Sample + classify + (last arriver per image) finish + (last image) finalize.
// eq segments ballot-compacted into a per-image stream; un/cnt/md accumulated
// via device-scope atomics. Cross-block visibility of the seg stream uses the
// release(threadfence)->counter->acquire(threadfence) pattern.
__global__ __launch_bounds__(256) void sample_finish_kernel(
                               const float* __restrict__ inputs,
                               const float* __restrict__ targets,
                               const float* __restrict__ images,
                               const float* __restrict__ depth_gt,
                               float* __restrict__ ws,
                               float2* __restrict__ segs,
                               float* __restrict__ out){
    __shared__ float sred[4];
    __shared__ unsigned flag1, flag2;
    int img  = blockIdx.y;
    int jb   = blockIdx.x;
    int tid  = threadIdx.x;
    int lane = tid & 63;
    int j    = jb * 256 + tid;
    const float* x   = images   + (size_t)img * 3 * NPIX;
    const float* inp = inputs   + (size_t)img * NPIX;
    const float* tgt = targets  + (size_t)img * NPIX;
    const float* dgt = depth_gt + (size_t)img * NPIX;

    float ev = 0.0f;
    if (tid < NSTRIPS) ev = ws[OFF_EDGE + img * NSTRIPS + tid];
    float thr2 = 0.01f * block_reduce_max(ev, sred);

    float mdiff = 0.0f, un = 0.0f, cntv = 0.0f;
    float d2a[3] = {0.f,0.f,0.f}, ada[3] = {0.f,0.f,0.f};
    bool  eqf[3] = {false,false,false};

    if (j < PAIRS){
        uint64_t base = ((uint64_t)(img * PAIRS + j)) << 10;
        bool pdir = (mix64(((uint64_t)(NIMG * PAIRS + img)) << 10) & 1ull) != 0ull;

        int sh = -1, sw = -1;
        float gxs = 0.f, gys = 0.f, e2s = 1.f;
        for (int att = 0; att < 900; ++att){
            uint64_t u = mix64(base + (uint64_t)att);
            uint32_t pix = (uint32_t)(u >> 44);       // 20-bit uniform
            int r = (int)(pix >> 10);
            int c = (int)(pix & (WW - 1));
            if (r == 0 || r >= HH-1 || c == 0 || c >= WW-1) continue;
            float gx, gy;
            sobel_at(x, r, c, gx, gy);
            float e2 = gx*gx + gy*gy;
            if (!(e2 >= thr2)) continue;
            float dg = dgt[r*WW + c];
            float tg = tgt[r*WW + c];
            if (!(dg > -0.001f && dg < 80.0f && tg != 80.0f)) continue;
            sh = r; sw = c; gxs = gx; gys = gy; e2s = e2;
            break;
        }

        if (sh >= 0){
            float inv = rsqrtf(e2s);
            float cmul = gxs * inv;
            float rmul = gys * inv;
            if (!pdir) cmul = -cmul;

            uint64_t u0 = mix64(base + 1000ull);
            uint64_t u1 = mix64(base + 1001ull);
            float dist[4];
            dist[0] = -(float)(2u + (uint32_t)(u0 & 0xFFFFFFFFull) % 29u);
            dist[1] = -(float)(2u + (uint32_t)(u0 >> 32) % 29u);
            dist[2] =  (float)(2u + (uint32_t)(u1 & 0xFFFFFFFFull) % 29u);
            dist[3] =  (float)(2u + (uint32_t)(u1 >> 32) % 29u);

            int rowc[4], colc[4];
            bool valid = true;
            #pragma unroll
            for (int k = 0; k < 4; ++k){
                int cc2 = sw + (int)rintf(dist[k] * cmul);
                int rr2 = sh + (int)rintf(dist[k] * rmul);
                if (cc2 < 0 || cc2 > WW-1 || rr2 < 0 || rr2 > HH-1) valid = false;
                colc[k] = min(max(cc2, 0), WW-1);
                rowc[k] = min(max(rr2, 0), HH-1);
            }

            if (valid){
                float t4[4], i4[4];
                #pragma unroll
                for (int k = 0; k < 4; ++k){
                    int p = rowc[k]*WW + colc[k];
                    t4[k] = tgt[p];
                    i4[k] = inp[p];
                }
                #pragma unroll
                for (int k = 0; k < 3; ++k){
                    float tA = t4[k], tB = t4[k+1];
                    float ratio = (tA + 1e-6f) / (tB + 1e-6f);
                    float adk = fabsf(tA - tB);
                    mdiff = fmaxf(mdiff, adk);
                    bool eq = (ratio < 1.03f) && (ratio > 0.9708737864077669f);
                    if (eq){
                        float d = i4[k] - i4[k+1];
                        d2a[k] = d*d; ada[k] = adk; eqf[k] = true;
                    } else {
                        float lab = (ratio >= 1.03f) ? 1.0f : -1.0f;
                        un += log1pf(expf((i4[k+1] - i4[k]) * lab));
                    }
                }
                cntv = 3.0f;
            }
        }
    }

    // ---- ballot-compact eq segments (1 atomic per wave) ----
    {
        unsigned long long m0 = __ballot(eqf[0]);
        unsigned long long m1 = __ballot(eqf[1]);
        unsigned long long m2 = __ballot(eqf[2]);
        int c0 = __popcll(m0), c1 = __popcll(m1), c2 = __popcll(m2);
        int wavetot = c0 + c1 + c2;
        unsigned basei = 0;
        if (lane == 0 && wavetot)
            basei = atomicAdd((unsigned int*)&ws[OFF_SEGC + img], (unsigned)wavetot);
        basei = (unsigned)__shfl((int)basei, 0);
        unsigned long long below = (lane == 63) ? ~0ull >> 1 : ((1ull << lane) - 1ull);
        below = (1ull << lane) - 1ull;   // lane<64, shift safe for lane<64? use mask
        float2* sp = segs + (size_t)img * SEGCAP;
        if (eqf[0]) sp[basei + __popcll(m0 & below)]           = make_float2(d2a[0], ada[0]);
        if (eqf[1]) sp[basei + c0 + __popcll(m1 & below)]      = make_float2(d2a[1], ada[1]);
        if (eqf[2]) sp[basei + c0 + c1 + __popcll(m2 & below)] = make_float2(d2a[2], ada[2]);
    }

    // ---- per-block accumulation into per-image atomics ----
    float mdb = block_reduce_max(mdiff, sred);
    float unb = block_reduce_sum(un, sred);
    float cnb = block_reduce_sum(cntv, sred);
    if (tid == 0){
        if (mdb > 0.0f) atomicMax((unsigned int*)&ws[OFF_MDI + img], __float_as_uint(mdb));
        atomicAdd(&ws[OFF_RES + img*2 + 0], unb);
        atomicAdd(&ws[OFF_RES + img*2 + 1], cnb);
        __threadfence();                                        // release
        unsigned old = atomicAdd((unsigned int*)&ws[OFF_DONE + img], 1u);
        flag1 = (old == (unsigned)(S1BLOCKS - 1)) ? 1u : 0u;
    }
    __syncthreads();

    // ---- last arriver for this image: finish eq part ----
    if (flag1){
        __threadfence();                                        // acquire
        float md = __uint_as_float(atomicAdd((unsigned int*)&ws[OFF_MDI + img], 0u));
        float inv = 1.0f / (md + 1e-6f);
        unsigned nseg = atomicAdd((unsigned int*)&ws[OFF_SEGC + img], 0u);
        const float2* sp = segs + (size_t)img * SEGCAP;
        float eqs = 0.0f;
        for (unsigned r = tid; r < nseg; r += 256){
            float2 s = sp[r];
            eqs += s.x * expf(-s.y * inv);
        }
        eqs = block_reduce_sum(eqs, sred);
        if (tid == 0){
            atomicAdd(&ws[OFF_RES + img*2 + 0], eqs);
            __threadfence();                                    // release
            unsigned o2 = atomicAdd((unsigned int*)&ws[OFF_IMGD], 1u);
            flag2 = (o2 == (unsigned)(NIMG - 1)) ? 1u : 0u;
        }
        __syncthreads();

        // ---- last image finisher: cross-image reduce -> out ----
        if (flag2){
            __threadfence();                                    // acquire
            float val = 0.0f, cv = 0.0f;
            if (tid < NIMG){
                float li = atomicAdd(&ws[OFF_RES + tid*2 + 0], 0.0f);
                float ci = atomicAdd(&ws[OFF_RES + tid*2 + 1], 0.0f);
                val = li / fmaxf(ci, 1.0f);
                cv  = ci;
            }
            for (int off = 4; off; off >>= 1){
                val += __shfl_down(val, off);
                cv  += __shfl_down(cv,  off);
            }
            if (tid == 0){
                out[0] = val / (float)NIMG;   // ALPHA = 1
                out[1] = cv  / (float)NIMG;
            }
        }
    }
}

extern "C" void kernel_launch(void* const* d_in, const int* in_sizes, int n_in,
                              void* d_out, int out_size, void* d_ws, size_t ws_size,
                              hipStream_t stream) {
    const float* inputs  = (const float*)d_in[0];
    const float* targets = (const float*)d_in[1];
    const float* images  = (const float*)d_in[2];
    const float* depth   = (const float*)d_in[3];
    float* out = (float*)d_out;

    float* ws    = (float*)d_ws;
    float2* segs = (float2*)((char*)d_ws + 65536);

    hipLaunchKernelGGL(edgemax_kernel, dim3(NSTRIPS/4, NIMG), dim3(256), 0, stream,
                       images, ws);
    hipLaunchKernelGGL(sample_finish_kernel, dim3(S1BLOCKS, NIMG), dim3(256), 0, stream,
                       inputs, targets, images, depth, ws, segs, out);
}

// Round 10
// 38.246 us; speedup vs baseline: 1.5296x; 1.5296x over previous
//
#include <hip/hip_runtime.h>
#include <math.h>
#include <stdint.h>

#define NIMG 8
#define HH 1024
#define WW 1024
#define NPIX (HH*WW)
#define PAIRS 10000
#define STRIP 8
#define NSTRIPS 128          // strips per image (rows 1..1022, 8 rows each)
#define S1BLOCKS 40          // sample blocks per image
#define WSLOTS (S1BLOCKS*4)  // per-wave partial slots per image (160)
#define FBLK 4               // finish blocks per image
#define QPAIRS (PAIRS/FBLK)  // 2500

// ws layout (floats):
// [OFF_EDGE .. +NIMG*NSTRIPS)  per-strip squared-sobel max   (1024)   plain stores
// [OFF_MD   .. +NIMG*WSLOTS)   per-wave maxdiff partials     (1280)   plain stores
// [OFF_RES  .. +16)            per-image {loss, cnt} atomic accum (zeroed by edgemax)
// [OFF_CTR]                    finish completion counter (uint, zeroed by edgemax)
// byte 65536:                recsA [NIMG*PAIRS] float4 (d2_0,d2_1,d2_2,un)
// byte 65536+NIMG*PAIRS*16:  recsB [NIMG*PAIRS] float4 (ad_0,ad_1,ad_2,cnt)
//
// XCD note: all three kernels use img = blockIdx.x & 7. Flat block ids
// round-robin the 8 XCDs, so each image's working set (ch0 image plane,
// records) stays in ONE XCD's 4 MB L2 across kernels — the rejection loop's
// sobel reads become L2 hits instead of L3.
#define OFF_EDGE 0
#define OFF_MD   1024
#define OFF_RES  4096
#define OFF_CTR  4112

__device__ __forceinline__ uint64_t mix64(uint64_t x){
    x += 0x9E3779B97F4A7C15ull;
    x = (x ^ (x >> 30)) * 0xBF58476D1CE4E5B9ull;
    x = (x ^ (x >> 27)) * 0x94D049BB133111EBull;
    return x ^ (x >> 31);
}

__device__ __forceinline__ float block_reduce_max(float v, float* sm){
    for (int off = 32; off; off >>= 1)
        v = fmaxf(v, __shfl_down(v, off));
    int wv = threadIdx.x >> 6, lane = threadIdx.x & 63;
    if (lane == 0) sm[wv] = v;
    __syncthreads();
    if (threadIdx.x == 0)
        sm[0] = fmaxf(fmaxf(sm[0], sm[1]), fmaxf(sm[2], sm[3]));
    __syncthreads();
    float r = sm[0];
    __syncthreads();
    return r;
}

__device__ __forceinline__ float block_reduce_sum(float v, float* sm){
    for (int off = 32; off; off >>= 1)
        v += __shfl_down(v, off);
    int wv = threadIdx.x >> 6, lane = threadIdx.x & 63;
    if (lane == 0) sm[wv] = v;
    __syncthreads();
    if (threadIdx.x == 0)
        sm[0] = sm[0] + sm[1] + sm[2] + sm[3];
    __syncthreads();
    float r = sm[0];
    __syncthreads();
    return r;
}

__device__ __forceinline__ void sobel_at(const float* __restrict__ x, int r, int c,
                                         float& gx, float& gy){
    const float* p0 = x + (size_t)(r-1)*WW + c;
    const float* p1 = x + (size_t)r*WW + c;
    const float* p2 = x + (size_t)(r+1)*WW + c;
    float a = p0[-1], b = p0[0], cc = p0[1];
    float d = p1[-1],             e = p1[1];
    float f = p2[-1], g = p2[0], h = p2[1];
    gx = (cc - a) + 2.0f*(e - d) + (h - f);
    gy = (a + 2.0f*b + cc) - (f + 2.0f*g + h);
}

__device__ __forceinline__ void load16(const float* __restrict__ p, float* d){
    const float4* q = (const float4*)p;
    float4 v0 = q[0], v1 = q[1], v2 = q[2], v3 = q[3];
    d[0]=v0.x; d[1]=v0.y; d[2]=v0.z; d[3]=v0.w;
    d[4]=v1.x; d[5]=v1.y; d[6]=v1.z; d[7]=v1.w;
    d[8]=v2.x; d[9]=v2.y; d[10]=v2.z; d[11]=v2.w;
    d[12]=v3.x; d[13]=v3.y; d[14]=v3.z; d[15]=v3.w;
}

// One wave owns a 1024-wide row span (16 cols/lane), rolls 3 rows in registers,
// separable sobel, cross-lane neighbors via shuffles, max of SQUARED magnitude.
// Block 0 also zeroes the atomic accumulator slots for this launch.
__global__ __launch_bounds__(256) void edgemax_kernel(const float* __restrict__ images,
                                                      float* __restrict__ ws){
    if (blockIdx.x == 0 && threadIdx.x < 17)
        ws[OFF_RES + threadIdx.x] = 0.0f;      // 16 res slots + ctr

    int img  = blockIdx.x & 7;                          // XCD-pinned
    int xb   = blockIdx.x >> 3;                         // 0..31
    const float* x = images + (size_t)img * 3 * NPIX;   // channel 0
    int wv   = threadIdx.x >> 6;
    int lane = threadIdx.x & 63;
    int strip = xb * 4 + wv;                            // 0..127
    int r0 = 1 + strip * STRIP;
    int r1 = min(r0 + STRIP - 1, HH - 2);
    int c0 = lane * 16;

    float a[16], b[16], n[16];
    load16(x + (size_t)(r0-1)*WW + c0, a);
    load16(x + (size_t)r0*WW + c0, b);

    float m = 0.0f;
    for (int r = r0; r <= r1; ++r){
        load16(x + (size_t)(r+1)*WW + c0, n);
        float sx[16], dy[16];
        #pragma unroll
        for (int i = 0; i < 16; ++i){
            sx[i] = a[i] + 2.0f*b[i] + n[i];
            dy[i] = a[i] - n[i];
        }
        float sxl = __shfl_up(sx[15], 1);
        float sxr = __shfl_down(sx[0], 1);
        float dyl = __shfl_up(dy[15], 1);
        float dyr = __shfl_down(dy[0], 1);
        #pragma unroll
        for (int j = 0; j < 16; ++j){
            float sl = (j == 0)  ? sxl : sx[j-1];
            float sr = (j == 15) ? sxr : sx[j+1];
            float dl = (j == 0)  ? dyl : dy[j-1];
            float dr = (j == 15) ? dyr : dy[j+1];
            float gx = sr - sl;
            float gy = dl + 2.0f*dy[j] + dr;
            float e2 = gx*gx + gy*gy;
            int c = c0 + j;
            if (c >= 1 && c <= WW-2) m = fmaxf(m, e2);
        }
        #pragma unroll
        for (int i = 0; i < 16; ++i){ a[i] = b[i]; b[i] = n[i]; }
    }
    for (int off = 32; off; off >>= 1)
        m = fmaxf(m, __shfl_down(m, off));
    if (lane == 0)
        ws[OFF_EDGE + img * NSTRIPS + strip] = m;
}

// 1 thread per pair, serial rejection (line-minimal). Single pass:
// classification spilled to records so no second scattered pass is needed.
__global__ __launch_bounds__(256) void sample_kernel(
                               const float* __restrict__ inputs,
                               const float* __restrict__ targets,
                               const float* __restrict__ images,
                               const float* __restrict__ depth_gt,
                               float* __restrict__ ws,
                               float4* __restrict__ recsA,
                               float4* __restrict__ recsB){
    __shared__ float sred[4];
    int img = blockIdx.x & 7;                 // XCD-pinned (same XCD as edgemax)
    int jb  = blockIdx.x >> 3;                // 0..39
    int tid = threadIdx.x;
    int j   = jb * 256 + tid;
    const float* x   = images   + (size_t)img * 3 * NPIX;
    const float* inp = inputs   + (size_t)img * NPIX;
    const float* tgt = targets  + (size_t)img * NPIX;
    const float* dgt = depth_gt + (size_t)img * NPIX;

    float ev = 0.0f;
    if (tid < NSTRIPS) ev = ws[OFF_EDGE + img * NSTRIPS + tid];
    float thr2 = 0.01f * block_reduce_max(ev, sred);

    float mdiff = 0.0f;
    float4 recA = make_float4(0.f, 0.f, 0.f, 0.f);   // d2[3], un
    float4 recB = make_float4(0.f, 0.f, 0.f, 0.f);   // ad[3], cnt

    if (j < PAIRS){
        uint64_t base = ((uint64_t)(img * PAIRS + j)) << 10;
        bool pdir = (mix64(((uint64_t)(NIMG * PAIRS + img)) << 10) & 1ull) != 0ull;

        int sh = -1, sw = -1;
        float gxs = 0.f, gys = 0.f, e2s = 1.f;
        for (int att = 0; att < 900; ++att){
            uint64_t u = mix64(base + (uint64_t)att);
            uint32_t pix = (uint32_t)(u >> 44);       // 20-bit uniform
            int r = (int)(pix >> 10);
            int c = (int)(pix & (WW - 1));
            if (r == 0 || r >= HH-1 || c == 0 || c >= WW-1) continue;
            float gx, gy;
            sobel_at(x, r, c, gx, gy);
            float e2 = gx*gx + gy*gy;
            if (!(e2 >= thr2)) continue;
            float dg = dgt[r*WW + c];
            float tg = tgt[r*WW + c];
            if (!(dg > -0.001f && dg < 80.0f && tg != 80.0f)) continue;
            sh = r; sw = c; gxs = gx; gys = gy; e2s = e2;
            break;
        }

        if (sh >= 0){
            float inv = rsqrtf(e2s);
            float cmul = gxs * inv;
            float rmul = gys * inv;
            if (!pdir) cmul = -cmul;

            uint64_t u0 = mix64(base + 1000ull);
            uint64_t u1 = mix64(base + 1001ull);
            float dist[4];
            dist[0] = -(float)(2u + (uint32_t)(u0 & 0xFFFFFFFFull) % 29u);
            dist[1] = -(float)(2u + (uint32_t)(u0 >> 32) % 29u);
            dist[2] =  (float)(2u + (uint32_t)(u1 & 0xFFFFFFFFull) % 29u);
            dist[3] =  (float)(2u + (uint32_t)(u1 >> 32) % 29u);

            int rowc[4], colc[4];
            bool valid = true;
            #pragma unroll
            for (int k = 0; k < 4; ++k){
                int cc2 = sw + (int)rintf(dist[k] * cmul);
                int rr2 = sh + (int)rintf(dist[k] * rmul);
                if (cc2 < 0 || cc2 > WW-1 || rr2 < 0 || rr2 > HH-1) valid = false;
                colc[k] = min(max(cc2, 0), WW-1);
                rowc[k] = min(max(rr2, 0), HH-1);
            }

            if (valid){
                float t4[4], i4[4];
                #pragma unroll
                for (int k = 0; k < 4; ++k){
                    int p = rowc[k]*WW + colc[k];
                    t4[k] = tgt[p];
                    i4[k] = inp[p];
                }
                float d2a[3], ada[3];
                float un = 0.0f;
                #pragma unroll
                for (int k = 0; k < 3; ++k){
                    float tA = t4[k], tB = t4[k+1];
                    float ratio = (tA + 1e-6f) / (tB + 1e-6f);
                    float adk = fabsf(tA - tB);
                    mdiff = fmaxf(mdiff, adk);
                    bool eq = (ratio < 1.03f) && (ratio > 0.9708737864077669f);
                    if (eq){
                        float d = i4[k] - i4[k+1];
                        d2a[k] = d*d; ada[k] = adk;
                    } else {
                        d2a[k] = 0.f; ada[k] = 0.f;
                        float lab = (ratio >= 1.03f) ? 1.0f : -1.0f;
                        un += log1pf(expf((i4[k+1] - i4[k]) * lab));
                    }
                }
                recA = make_float4(d2a[0], d2a[1], d2a[2], un);
                recB = make_float4(ada[0], ada[1], ada[2], 3.0f);
            }
        }
        recsA[img * PAIRS + j] = recA;
        recsB[img * PAIRS + j] = recB;
    }

    for (int off = 32; off; off >>= 1)
        mdiff = fmaxf(mdiff, __shfl_down(mdiff, off));
    if ((tid & 63) == 0)
        ws[OFF_MD + img * WSLOTS + jb*4 + (tid >> 6)] = mdiff;
}

// 4 blocks per image (XCD-pinned): redundant md reduce, quarter-scan of
// records, atomic accumulation into per-image slots; the LAST block
// (completion counter) performs the final cross-image reduce. All cross-block
// communication is device-scope atomics — fences confined to this tiny kernel.
__global__ __launch_bounds__(256) void finish_kernel(
                               float* __restrict__ ws,
                               const float4* __restrict__ recsA,
                               const float4* __restrict__ recsB,
                               float* __restrict__ out){
    __shared__ float sred[4];
    __shared__ unsigned lastflag;
    int img = blockIdx.x & 7;                 // XCD-pinned (records L2-local)
    int q   = blockIdx.x >> 3;                // 0..3
    int tid = threadIdx.x;

    float mv = 0.0f;
    if (tid < WSLOTS) mv = ws[OFF_MD + img * WSLOTS + tid];
    float md = block_reduce_max(mv, sred);
    float inv = 1.0f / (md + 1e-6f);

    float loss = 0.0f, cnt = 0.0f;
    int base = img * PAIRS + q * QPAIRS;
    for (int r = tid; r < QPAIRS; r += 256){
        float4 A = recsA[base + r];
        float4 B = recsB[base + r];
        loss += A.w
              + A.x * expf(-B.x * inv)
              + A.y * expf(-B.y * inv)
              + A.z * expf(-B.z * inv);
        cnt  += B.w;
    }
    loss = block_reduce_sum(loss, sred);
    cnt  = block_reduce_sum(cnt, sred);

    if (tid == 0){
        atomicAdd(&ws[OFF_RES + img*2 + 0], loss);
        atomicAdd(&ws[OFF_RES + img*2 + 1], cnt);
        __threadfence();                               // release
        unsigned old = atomicAdd((unsigned int*)&ws[OFF_CTR], 1u);
        lastflag = (old == (unsigned)(NIMG*FBLK - 1)) ? 1u : 0u;
    }
    __syncthreads();

    if (lastflag){
        __threadfence();                               // acquire
        float val = 0.0f, cv = 0.0f;
        if (tid < NIMG){
            float li = atomicAdd(&ws[OFF_RES + tid*2 + 0], 0.0f);  // coherent read
            float ci = atomicAdd(&ws[OFF_RES + tid*2 + 1], 0.0f);
            val = li / fmaxf(ci, 1.0f);
            cv  = ci;
        }
        for (int off = 4; off; off >>= 1){
            val += __shfl_down(val, off);
            cv  += __shfl_down(cv,  off);
        }
        if (tid == 0){
            out[0] = val / (float)NIMG;   // ALPHA = 1
            out[1] = cv  / (float)NIMG;
        }
    }
}

extern "C" void kernel_launch(void* const* d_in, const int* in_sizes, int n_in,
                              void* d_out, int out_size, void* d_ws, size_t ws_size,
                              hipStream_t stream) {
    const float* inputs  = (const float*)d_in[0];
    const float* targets = (const float*)d_in[1];
    const float* images  = (const float*)d_in[2];
    const float* depth   = (const float*)d_in[3];
    float* out = (float*)d_out;

    float* ws     = (float*)d_ws;
    float4* recsA = (float4*)((char*)d_ws + 65536);
    float4* recsB = recsA + (size_t)NIMG * PAIRS;

    hipLaunchKernelGGL(edgemax_kernel, dim3(NSTRIPS/4 * NIMG), dim3(256), 0, stream,
                       images, ws);
    hipLaunchKernelGGL(sample_kernel, dim3(S1BLOCKS * NIMG), dim3(256), 0, stream,
                       inputs, targets, images, depth, ws, recsA, recsB);
    hipLaunchKernelGGL(finish_kernel, dim3(NIMG * FBLK), dim3(256), 0, stream,
                       ws, recsA, recsB, out);
}